// Round 2
// 878.155 us; speedup vs baseline: 1.2863x; 1.2863x over previous
//
#include <hip/hip_runtime.h>
#include <math.h>

#define NB    8
#define NQ    200
#define NCLS  81
#define HM    256
#define WM    256
#define SH    192   // scaled_h (crop rows)
#define SW    256   // scaled_w (crop cols)
#define OH    384   // origin_h
#define OW    512   // origin_w
#define NTOP  100
#define MIN_SCORE 0.1

#define BAND_OUT 48               // output rows per block
#define NBANDS   (OH / BAND_OUT)  // 8
#define BAND_IN  26               // BAND_OUT/2 + 2 input rows incl. clamped halo

typedef float floatx4 __attribute__((ext_vector_type(4)));  // native vec for nontemporal builtins

__device__ __forceinline__ float sigf(float x) {
    float e = __expf(-x);                    // v_exp_f32 (fast, ~2 ulp)
    return __builtin_amdgcn_rcpf(1.0f + e);  // v_rcp_f32 (~1 ulp); sigmoid in (0,1)
}

// Kernel 1: per (b,q) softmax score + argmax class. Double precision so that
// "score > 0.1" validity matches the numpy reference (a flip costs absmax~80).
__global__ void k_scores(const float* __restrict__ cp,
                         double* __restrict__ sc, int* __restrict__ cls) {
    int i = blockIdx.x * blockDim.x + threadIdx.x;
    if (i >= NB * NQ) return;
    const float* p = cp + (size_t)i * NCLS;
    float l[NCLS];
    #pragma unroll
    for (int c = 0; c < NCLS; ++c) l[c] = p[c];
    double M = (double)l[0];
    for (int c = 1; c < NCLS; ++c) M = fmax(M, (double)l[c]);
    double Z = 0.0;
    for (int c = 0; c < NCLS; ++c) Z += exp((double)l[c] - M);
    float best = l[0]; int bi = 0;
    for (int c = 1; c < NCLS - 1; ++c)      // drop last class for score/argmax
        if (l[c] > best) { best = l[c]; bi = c; }
    sc[i]  = exp((double)best - M) / Z;
    cls[i] = bi;
}

// Kernel 2: exact top-k (descending, ties -> lower index) via rank counting.
__global__ void k_topk(const double* __restrict__ sc, const int* __restrict__ cls,
                       float* __restrict__ out_scores, float* __restrict__ out_classes,
                       float* __restrict__ out_valid,
                       int* __restrict__ top_q, float* __restrict__ top_vf) {
    int b = blockIdx.x;
    __shared__ double s[NQ];
    int t = threadIdx.x;
    if (t < NQ) s[t] = sc[b * NQ + t];
    __syncthreads();
    if (t < NQ) {
        double mine = s[t];
        int rank = 0;
        for (int j = 0; j < NQ; ++j) {
            double v = s[j];
            rank += (v > mine) || (v == mine && j < t);
        }
        if (rank < NTOP) {
            int o = b * NTOP + rank;
            bool valid = mine > MIN_SCORE;
            out_scores[o]  = valid ? (float)mine : 0.0f;
            out_classes[o] = valid ? (float)cls[b * NQ + t] : -1.0f;
            out_valid[o]   = valid ? 1.0f : 0.0f;
            top_q[o]  = t;
            top_vf[o] = valid ? 1.0f : 0.0f;
        }
    }
}

// Kernel 3: one block per (mask, 48-row output band).
// Stage BAND_IN=26 sigmoid-activated input rows in LDS (sigmoid computed ONCE
// per input pixel instead of 4x per output pixel = 16x fewer transcendentals),
// then bilinear 2x upsample from LDS with floatx4 nontemporal stores.
// 2x bilinear (jax.image.resize, clamp-to-edge): for output coord o,
// u = o*0.5 - 0.25, idx0 = (o-1)>>1 (arith shift), frac = (o&1)? 0.25 : 0.75.
__global__ __launch_bounds__(256)
void k_resize(const float* __restrict__ mask_preds,
              const int* __restrict__ top_q,
              const float* __restrict__ top_vf,
              float* __restrict__ out_masks) {
    int band = blockIdx.x;              // 0..7
    int m    = blockIdx.y;              // 0..799 (b*100 + k)
    int t    = threadIdx.x;             // 0..255
    int ys   = band * BAND_OUT;
    float vf = top_vf[m];
    float* outp = out_masks + (size_t)m * OH * OW;

    if (vf == 0.0f) {
        // invalid mask: no gather, no sigmoid — just stream zeros
        floatx4 z = (floatx4)(0.0f);
        floatx4* o4 = (floatx4*)(outp + (size_t)ys * OW);
        #pragma unroll
        for (int i = 0; i < (BAND_OUT * OW / 4) / 256; ++i)       // 24 iters
            __builtin_nontemporal_store(z, o4 + i * 256 + t);
        return;
    }

    int b = m / NTOP;
    int q = top_q[m];
    const float* base = mask_preds + (size_t)(b * NQ + q) * HM * WM;
    int rbase = (ys >> 1) - 1;          // first (unclamped) input row this band needs

    __shared__ float s[BAND_IN][WM];    // 26.6 KB -> 6 blocks/CU, 24 waves/CU

    // Stage: 4 rows per iteration; rsub is wave-uniform (t>>6) so the tail
    // predicate is non-divergent. float4 coalesced loads, sigmoid once.
    int rsub = t >> 6;                  // 0..3 == wave id
    int c4   = (t & 63) << 2;           // 0,4,...,252
    #pragma unroll
    for (int it = 0; it < 7; ++it) {
        int r = it * 4 + rsub;
        if (r < BAND_IN) {
            int gr = min(max(rbase + r, 0), SH - 1);   // clamp-to-edge halo
            floatx4 v = *(const floatx4*)(base + (size_t)gr * WM + c4);
            s[r][c4 + 0] = sigf(v.x);
            s[r][c4 + 1] = sigf(v.y);
            s[r][c4 + 2] = sigf(v.z);
            s[r][c4 + 3] = sigf(v.w);
        }
    }
    __syncthreads();

    // Each thread: 4 output px (one float4) per row, 24 rows.
    // x = 4*xt + {0,1,2,3} needs input cols {2xt-1, 2xt, 2xt+1, 2xt+2}.
    int half = t >> 7;                  // threads split across row pairs
    int xt   = t & 127;                 // float4 index within the row
    int c1 = 2 * xt;
    int c0 = max(c1 - 1, 0);
    int c2 = min(c1 + 1, SW - 1);
    int c3 = min(c1 + 2, SW - 1);

    for (int yy = half; yy < BAND_OUT; yy += 2) {
        int y   = ys + yy;
        int iy0 = ((y - 1) >> 1) - rbase;      // LDS row index (y=0 -> 0 via rbase=-1)
        int iy1 = iy0 + 1;
        float ty = (y & 1) ? 0.25f : 0.75f;

        float u0 = s[iy0][c0], u1 = s[iy0][c1], u2 = s[iy0][c2], u3 = s[iy0][c3];
        float w0 = s[iy1][c0], w1 = s[iy1][c1], w2 = s[iy1][c2], w3 = s[iy1][c3];

        // horizontal lerps (px0:(c0,c1,.75) px1:(c1,c2,.25) px2:(c1,c2,.75) px3:(c2,c3,.25))
        float h0t = u0 + 0.75f * (u1 - u0);
        float h1t = u1 + 0.25f * (u2 - u1);
        float h2t = u1 + 0.75f * (u2 - u1);
        float h3t = u2 + 0.25f * (u3 - u2);
        float h0b = w0 + 0.75f * (w1 - w0);
        float h1b = w1 + 0.25f * (w2 - w1);
        float h2b = w1 + 0.75f * (w2 - w1);
        float h3b = w2 + 0.25f * (w3 - w2);

        floatx4 o;
        o.x = (h0t + ty * (h0b - h0t)) * vf;
        o.y = (h1t + ty * (h1b - h1t)) * vf;
        o.z = (h2t + ty * (h2b - h2t)) * vf;
        o.w = (h3t + ty * (h3b - h3t)) * vf;
        __builtin_nontemporal_store(o, (floatx4*)(outp + (size_t)y * OW) + xt);
    }
}

extern "C" void kernel_launch(void* const* d_in, const int* in_sizes, int n_in,
                              void* d_out, int out_size, void* d_ws, size_t ws_size,
                              hipStream_t stream) {
    (void)in_sizes; (void)n_in; (void)out_size; (void)ws_size;
    const float* mask_preds  = (const float*)d_in[0];
    const float* class_preds = (const float*)d_in[1];
    // d_in[2..5] are the (fixed) scalars 192,256,384,512 — compiled in.

    float* out        = (float*)d_out;
    float* out_masks  = out;                                    // 8*100*384*512
    float* out_scores = out + (size_t)NB * NTOP * OH * OW;      // 800
    float* out_classes= out_scores + NB * NTOP;                 // 800 (as float)
    float* out_valid  = out_classes + NB * NTOP;                // 800 (as float)

    char* ws = (char*)d_ws;
    double* sc    = (double*)ws;                                // 1600 * 8B
    int*    cls   = (int*)(ws + 1600 * 8);                      // 1600 * 4B
    int*    top_q = (int*)(ws + 1600 * 8 + 1600 * 4);           // 800  * 4B
    float*  top_vf= (float*)(ws + 1600 * 8 + 1600 * 4 + 800*4); // 800  * 4B

    k_scores<<<dim3((NB * NQ + 255) / 256), dim3(256), 0, stream>>>(class_preds, sc, cls);
    k_topk  <<<dim3(NB), dim3(256), 0, stream>>>(sc, cls, out_scores, out_classes,
                                                 out_valid, top_q, top_vf);
    k_resize<<<dim3(NBANDS, NB * NTOP), dim3(256), 0, stream>>>(mask_preds, top_q,
                                                                top_vf, out_masks);
}